// Round 7
// baseline (246.210 us; speedup 1.0000x reference)
//
#include <hip/hip_runtime.h>
#include <math.h>

#define Bn 4
#define Tn 12
#define Nn 512
#define Dn 128
#define Ln 4
#define Hn 64
#define NNe (Nn*Nn)

typedef __attribute__((ext_vector_type(8))) short short8;
typedef __attribute__((ext_vector_type(4))) float f32x4;

__device__ __forceinline__ unsigned short f2bf(float f) {
    unsigned int u = __float_as_uint(f);
    unsigned int r = (u + 0x7FFF + ((u >> 16) & 1)) >> 16;   // RNE
    return (unsigned short)r;
}
__device__ __forceinline__ float bf2f(unsigned short s) {
    return __uint_as_float(((unsigned int)s) << 16);
}

// ============ K1: fused encoder: x -> h -> agg -> sp/tp ============
// 4 rows/block, grid 512 (2 blocks/CU, 8 waves/CU): R6 showed 256 blocks = 1 wave/SIMD
// = pure exposed latency (VALUBusy 5%). No manual prefetch (R5: spilled at VGPR=256).
__global__ __launch_bounds__(256, 2) void k_enc(
    const float* __restrict__ x, const float* __restrict__ W1, const float* __restrict__ b1,
    const float* __restrict__ W2, const float* __restrict__ b2,
    const float* __restrict__ Ws1, const float* __restrict__ bs1,
    unsigned short* __restrict__ spb, unsigned short* __restrict__ tpb,
    unsigned int* __restrict__ maxslot)
{
    __shared__ float hl[4*Ln*Hn];    // [row][lag][64] = 4 KB
    __shared__ float agg[4*Dn];      // [row][128]     = 2 KB
    int tid = threadIdx.x;
    int bx = blockIdx.x;
    int wv = __builtin_amdgcn_readfirstlane(tid >> 6);
    int lane = tid & 63;
    if (bx == 0 && tid < Bn) maxslot[tid] = 0u;
    int r0g = bx * 4;                       // 4 rows, never straddles a batch
    int bb = r0g >> 9, n0 = r0g & 511;

    // --- A: wave = lag; lane = h-channel; x rows via wave-uniform (scalar) loads ---
    {
        int lag = wv;
        const float* xr = x + ((size_t)(bb*Tn + (Tn-1-lag))*Nn + n0) * Dn;
        const float* Wp = W1 + (size_t)lag*Dn*Hn;
        float acc[4] = {};
        for (int d4 = 0; d4 < 32; ++d4) {
            float4 xv[4];
            #pragma unroll
            for (int r = 0; r < 4; ++r) xv[r] = *(const float4*)(xr + r*Dn + d4*4);  // uniform
            #pragma unroll
            for (int u = 0; u < 4; ++u) {
                float w = Wp[(d4*4+u)*Hn + lane];
                #pragma unroll
                for (int r = 0; r < 4; ++r) acc[r] += ((const float*)&xv[r])[u]*w;
            }
        }
        float bv = b1[lag*Hn + lane];
        #pragma unroll
        for (int r = 0; r < 4; ++r) hl[(r*4 + lag)*64 + lane] = fmaxf(acc[r]+bv, 0.f);
    }
    __syncthreads();

    // --- B: wave = (row-pair, d-half); lane = d; 2 rows share each weight load ---
    {
        int r0 = (wv >> 1) * 2;
        int d  = (wv & 1) * 64 + lane;
        float acc0 = 0.f, acc1 = 0.f;
        for (int l = 0; l < Ln; ++l) {
            const float* h0 = hl + (r0*4 + l)*64;
            const float* h1 = hl + ((r0+1)*4 + l)*64;
            const float* Wp = W2 + (size_t)l*Hn*Dn + d;
            for (int h4 = 0; h4 < 16; ++h4) {
                float4 hv0 = *(const float4*)(h0 + h4*4);    // LDS broadcast
                float4 hv1 = *(const float4*)(h1 + h4*4);
                #pragma unroll
                for (int u = 0; u < 4; ++u) {
                    float w = Wp[(size_t)(h4*4+u)*Dn];       // coalesced 4B/lane
                    acc0 += ((const float*)&hv0)[u]*w;
                    acc1 += ((const float*)&hv1)[u]*w;
                }
            }
        }
        float b2s = b2[d] + b2[Dn+d] + b2[2*Dn+d] + b2[3*Dn+d];
        agg[r0*Dn + d]     = 0.25f*(acc0 + b2s);
        agg[(r0+1)*Dn + d] = 0.25f*(acc1 + b2s);
    }
    __syncthreads();

    // --- C: wave = (k-half, tgt); lane = k; all 4 rows in registers per weight load ---
    {
        int tgt = wv & 1;
        int k   = (wv >> 1)*64 + lane;
        float acc[4] = {};
        const float* Wbase = Ws1 + (size_t)tgt*Dn*Dn + k;   // Ws1[(tgt*128 + d)*128 + k]
        for (int d4 = 0; d4 < 32; ++d4) {
            float4 av[4];
            #pragma unroll
            for (int r = 0; r < 4; ++r) av[r] = *(const float4*)(agg + r*Dn + d4*4);  // broadcast
            #pragma unroll
            for (int u = 0; u < 4; ++u) {
                float w = Wbase[(size_t)(d4*4+u)*Dn];        // coalesced 4B/lane
                #pragma unroll
                for (int r = 0; r < 4; ++r) acc[r] += ((const float*)&av[r])[u]*w;
            }
        }
        float bsv = (tgt == 0) ? bs1[k] : 0.f;               // fold bs1 into sp
        unsigned short* dst = (tgt == 0 ? spb : tpb);
        #pragma unroll
        for (int r = 0; r < 4; ++r)
            dst[(size_t)(r0g + r)*Dn + k] = f2bf(acc[r] + bsv);
    }
}

// ============ K2: pairwise scorer -> adj bf16 row-major + transposed ============
__global__ __launch_bounds__(256) void k_score(
    const unsigned short* __restrict__ spb, const unsigned short* __restrict__ tpb,
    const float* __restrict__ Ws2, const float* __restrict__ bs2,
    unsigned short* __restrict__ adj_b, unsigned short* __restrict__ adj_bt)
{
    __shared__ float spl[64*132];                     // 33 KB
    __shared__ unsigned short tplT[Dn*72];            // 18 KB
    int tid = threadIdx.x;
    int wv = __builtin_amdgcn_readfirstlane(tid >> 6);
    int lane = tid & 63;
    int bz = blockIdx.z;
    int i0b = blockIdx.y * 64, j0b = blockIdx.x * 64;
    const unsigned short* spr = spb + (size_t)bz*Nn*Dn;
    const unsigned short* tpr = tpb + (size_t)bz*Nn*Dn;

    for (int v = tid; v < 1024; v += 256) {           // sp tile: bf16 -> fp32 LDS
        int row = v >> 4, c = v & 15;
        const unsigned short* src = spr + (size_t)(i0b+row)*Dn + c*8;
        ushort4 u0 = *(const ushort4*)src;
        ushort4 u1 = *(const ushort4*)(src + 4);
        float4 f0 = { bf2f(u0.x), bf2f(u0.y), bf2f(u0.z), bf2f(u0.w) };
        float4 f1 = { bf2f(u1.x), bf2f(u1.y), bf2f(u1.z), bf2f(u1.w) };
        *(float4*)&spl[row*132 + c*8]     = f0;
        *(float4*)&spl[row*132 + c*8 + 4] = f1;
    }
    {   // tp tile transposed, bf16
        int j = tid & 63, kq = tid >> 6;
        for (int p = 0; p < 4; ++p) {
            int k8 = p*4 + kq;
            short8 tv = *(const short8*)(tpr + (size_t)(j0b+j)*Dn + k8*8);
            #pragma unroll
            for (int t = 0; t < 8; ++t) tplT[(k8*8+t)*72 + j] = (unsigned short)tv[t];
        }
    }
    __syncthreads();

    int iq = lane >> 4, jq = lane & 15;
    int iw = wv*16 + iq*4;
    float acc[4][4] = {};
    for (int k8 = 0; k8 < 16; ++k8) {
        float4 wa = *(const float4*)(Ws2 + k8*8);     // uniform -> scalar path
        float4 wb = *(const float4*)(Ws2 + k8*8 + 4);
        float4 sA[4], sB[4];
        #pragma unroll
        for (int ii = 0; ii < 4; ++ii) {
            sA[ii] = *(const float4*)&spl[(iw+ii)*132 + k8*8];
            sB[ii] = *(const float4*)&spl[(iw+ii)*132 + k8*8 + 4];
        }
        ushort4 t4[8];
        #pragma unroll
        for (int kk = 0; kk < 8; ++kk) t4[kk] = *(const ushort4*)&tplT[(k8*8+kk)*72 + jq*4];
        #pragma unroll
        for (int kk = 0; kk < 8; ++kk) {
            float w = (kk < 4) ? ((const float*)&wa)[kk] : ((const float*)&wb)[kk-4];
            float tv0 = bf2f(t4[kk].x), tv1 = bf2f(t4[kk].y);
            float tv2 = bf2f(t4[kk].z), tv3 = bf2f(t4[kk].w);
            #pragma unroll
            for (int ii = 0; ii < 4; ++ii) {
                float s = (kk < 4) ? ((const float*)&sA[ii])[kk] : ((const float*)&sB[ii])[kk-4];
                acc[ii][0] += fmaxf(s + tv0, 0.f)*w;
                acc[ii][1] += fmaxf(s + tv1, 0.f)*w;
                acc[ii][2] += fmaxf(s + tv2, 0.f)*w;
                acc[ii][3] += fmaxf(s + tv3, 0.f)*w;
            }
        }
    }
    float bsv = bs2[0];
    int i0 = i0b + iw;
    int j0 = j0b + jq*4;
    float vals[4][4];
    #pragma unroll
    for (int ii = 0; ii < 4; ++ii) {
        int i = i0 + ii;
        #pragma unroll
        for (int jj = 0; jj < 4; ++jj) {
            float z = acc[ii][jj] + bsv;
            float sc = 1.f/(1.f + __expf(-z));
            int j = j0 + jj;
            vals[ii][jj] = (sc > 0.1f && i != j) ? sc : 0.f;
        }
    }
    size_t base = (size_t)bz << 18;
    #pragma unroll
    for (int ii = 0; ii < 4; ++ii) {
        ushort4 rv = make_ushort4(f2bf(vals[ii][0]), f2bf(vals[ii][1]),
                                  f2bf(vals[ii][2]), f2bf(vals[ii][3]));
        *(ushort4*)(adj_b + base + (size_t)(i0+ii)*Nn + j0) = rv;
    }
    #pragma unroll
    for (int jj = 0; jj < 4; ++jj) {
        ushort4 cv = make_ushort4(f2bf(vals[0][jj]), f2bf(vals[1][jj]),
                                  f2bf(vals[2][jj]), f2bf(vals[3][jj]));
        *(ushort4*)(adj_bt + base + (size_t)(j0+jj)*Nn + i0) = cv;
    }
}

// ============ K3: a2 = adj @ adj (MFMA, 64x64 tile, BK=64, reg double-buffer) ============
__global__ __launch_bounds__(256) void k_mm1(
    const unsigned short* __restrict__ adj_b, const unsigned short* __restrict__ adj_bt,
    unsigned short* __restrict__ a2b)
{
    __shared__ unsigned short Als[64*72];
    __shared__ unsigned short Bls[64*72];
    int tid = threadIdx.x;
    int wv = __builtin_amdgcn_readfirstlane(tid >> 6);
    int lane = tid & 63;
    int b = blockIdx.z, i0 = blockIdx.y*64, j0 = blockIdx.x*64;
    size_t base = (size_t)b << 18;
    const unsigned short* Ab = adj_b + base;
    const unsigned short* Bb = adj_bt + base;
    int wm = wv >> 1, wn = wv & 1;
    int m = lane & 15, q = lane >> 4;
    int sr = tid >> 2, sc = (tid & 3)*16;
    f32x4 acc[2][2];
    #pragma unroll
    for (int mt = 0; mt < 2; ++mt)
        #pragma unroll
        for (int nt = 0; nt < 2; ++nt) acc[mt][nt] = (f32x4){0.f,0.f,0.f,0.f};
    short8 pa0, pa1, pb0, pb1;
    pa0 = *(const short8*)(Ab + (size_t)(i0+sr)*Nn + sc);
    pa1 = *(const short8*)(Ab + (size_t)(i0+sr)*Nn + sc + 8);
    pb0 = *(const short8*)(Bb + (size_t)(j0+sr)*Nn + sc);
    pb1 = *(const short8*)(Bb + (size_t)(j0+sr)*Nn + sc + 8);
    for (int kt = 0; kt < 8; ++kt) {
        *(short8*)&Als[sr*72 + sc]     = pa0;
        *(short8*)&Als[sr*72 + sc + 8] = pa1;
        *(short8*)&Bls[sr*72 + sc]     = pb0;
        *(short8*)&Bls[sr*72 + sc + 8] = pb1;
        __syncthreads();
        if (kt < 7) {
            int k0 = (kt+1)*64;
            pa0 = *(const short8*)(Ab + (size_t)(i0+sr)*Nn + k0 + sc);
            pa1 = *(const short8*)(Ab + (size_t)(i0+sr)*Nn + k0 + sc + 8);
            pb0 = *(const short8*)(Bb + (size_t)(j0+sr)*Nn + k0 + sc);
            pb1 = *(const short8*)(Bb + (size_t)(j0+sr)*Nn + k0 + sc + 8);
        }
        #pragma unroll
        for (int ks = 0; ks < 2; ++ks) {
            short8 af[2], bg[2];
            #pragma unroll
            for (int mt = 0; mt < 2; ++mt) af[mt] = *(const short8*)&Als[(wm*32+mt*16+m)*72 + ks*32 + q*8];
            #pragma unroll
            for (int nt = 0; nt < 2; ++nt) bg[nt] = *(const short8*)&Bls[(wn*32+nt*16+m)*72 + ks*32 + q*8];
            #pragma unroll
            for (int mt = 0; mt < 2; ++mt)
                #pragma unroll
                for (int nt = 0; nt < 2; ++nt)
                    acc[mt][nt] = __builtin_amdgcn_mfma_f32_16x16x32_bf16(af[mt], bg[nt], acc[mt][nt], 0, 0, 0);
        }
        __syncthreads();
    }
    int col = lane & 15, rq = lane >> 4;
    #pragma unroll
    for (int mt = 0; mt < 2; ++mt)
        #pragma unroll
        for (int nt = 0; nt < 2; ++nt)
            #pragma unroll
            for (int reg = 0; reg < 4; ++reg) {
                int i = i0 + wm*32 + mt*16 + rq*4 + reg;
                int j = j0 + wn*32 + nt*16 + col;
                a2b[base + (size_t)i*Nn + j] = f2bf(acc[mt][nt][reg]);
            }
}

// ============ K4: out = adj + 0.5*a2 + 0.25*(a2@adj), + per-batch max ============
__global__ __launch_bounds__(256) void k_mm2(
    const unsigned short* __restrict__ adj_b, const unsigned short* __restrict__ adj_bt,
    const unsigned short* __restrict__ a2b,
    float* __restrict__ out, unsigned int* __restrict__ maxslot)
{
    __shared__ unsigned short Als[64*72];
    __shared__ unsigned short Bls[64*72];
    __shared__ float red[4];
    int tid = threadIdx.x;
    int wv = __builtin_amdgcn_readfirstlane(tid >> 6);
    int lane = tid & 63;
    int b = blockIdx.z, i0 = blockIdx.y*64, j0 = blockIdx.x*64;
    size_t base = (size_t)b << 18;
    const unsigned short* Ab = a2b + base;       // A = a2
    const unsigned short* Bb = adj_bt + base;    // B = adj (transposed layout)
    int wm = wv >> 1, wn = wv & 1;
    int m = lane & 15, q = lane >> 4;
    int sr = tid >> 2, sc = (tid & 3)*16;
    f32x4 acc[2][2];
    #pragma unroll
    for (int mt = 0; mt < 2; ++mt)
        #pragma unroll
        for (int nt = 0; nt < 2; ++nt) acc[mt][nt] = (f32x4){0.f,0.f,0.f,0.f};
    short8 pa0, pa1, pb0, pb1;
    pa0 = *(const short8*)(Ab + (size_t)(i0+sr)*Nn + sc);
    pa1 = *(const short8*)(Ab + (size_t)(i0+sr)*Nn + sc + 8);
    pb0 = *(const short8*)(Bb + (size_t)(j0+sr)*Nn + sc);
    pb1 = *(const short8*)(Bb + (size_t)(j0+sr)*Nn + sc + 8);
    for (int kt = 0; kt < 8; ++kt) {
        *(short8*)&Als[sr*72 + sc]     = pa0;
        *(short8*)&Als[sr*72 + sc + 8] = pa1;
        *(short8*)&Bls[sr*72 + sc]     = pb0;
        *(short8*)&Bls[sr*72 + sc + 8] = pb1;
        __syncthreads();
        if (kt < 7) {
            int k0 = (kt+1)*64;
            pa0 = *(const short8*)(Ab + (size_t)(i0+sr)*Nn + k0 + sc);
            pa1 = *(const short8*)(Ab + (size_t)(i0+sr)*Nn + k0 + sc + 8);
            pb0 = *(const short8*)(Bb + (size_t)(j0+sr)*Nn + k0 + sc);
            pb1 = *(const short8*)(Bb + (size_t)(j0+sr)*Nn + k0 + sc + 8);
        }
        #pragma unroll
        for (int ks = 0; ks < 2; ++ks) {
            short8 af[2], bg[2];
            #pragma unroll
            for (int mt = 0; mt < 2; ++mt) af[mt] = *(const short8*)&Als[(wm*32+mt*16+m)*72 + ks*32 + q*8];
            #pragma unroll
            for (int nt = 0; nt < 2; ++nt) bg[nt] = *(const short8*)&Bls[(wn*32+nt*16+m)*72 + ks*32 + q*8];
            #pragma unroll
            for (int mt = 0; mt < 2; ++mt)
                #pragma unroll
                for (int nt = 0; nt < 2; ++nt)
                    acc[mt][nt] = __builtin_amdgcn_mfma_f32_16x16x32_bf16(af[mt], bg[nt], acc[mt][nt], 0, 0, 0);
        }
        __syncthreads();
    }
    int col = lane & 15, rq = lane >> 4;
    float lmax = 0.f;
    const unsigned short* adjp = adj_b + base;
    #pragma unroll
    for (int mt = 0; mt < 2; ++mt)
        #pragma unroll
        for (int nt = 0; nt < 2; ++nt)
            #pragma unroll
            for (int reg = 0; reg < 4; ++reg) {
                int i = i0 + wm*32 + mt*16 + rq*4 + reg;
                int j = j0 + wn*32 + nt*16 + col;
                size_t off = (size_t)i*Nn + j;
                float e = bf2f(adjp[off]) + 0.5f*bf2f(Ab[off]) + 0.25f*acc[mt][nt][reg];
                out[base + off] = e;
                lmax = fmaxf(lmax, e);
            }
    #pragma unroll
    for (int s = 1; s < 64; s <<= 1) lmax = fmaxf(lmax, __shfl_xor(lmax, s, 64));
    if (lane == 0) red[wv] = lmax;
    __syncthreads();
    if (tid == 0) {
        float mx = fmaxf(fmaxf(red[0], red[1]), fmaxf(red[2], red[3]));
        atomicMax(maxslot + b, __float_as_uint(mx));
    }
}

// ============ K5: out /= (max + 1e-8) ============
__global__ __launch_bounds__(256) void k_norm(float* __restrict__ out,
                                              const unsigned int* __restrict__ maxslot)
{
    int idx = blockIdx.x*256 + threadIdx.x;   // float4 index; 65536 per batch
    int b = idx >> 16;
    float m = __uint_as_float(maxslot[b]);
    float inv = 1.f/(m + 1e-8f);
    float4* p = (float4*)out + idx;
    float4 v = *p;
    v.x *= inv; v.y *= inv; v.z *= inv; v.w *= inv;
    *p = v;
}

extern "C" void kernel_launch(void* const* d_in, const int* in_sizes, int n_in,
                              void* d_out, int out_size, void* d_ws, size_t ws_size,
                              hipStream_t stream) {
    const float* x   = (const float*)d_in[0];
    const float* W1  = (const float*)d_in[1];
    const float* b1  = (const float*)d_in[2];
    const float* W2  = (const float*)d_in[3];
    const float* b2  = (const float*)d_in[4];
    const float* Ws1 = (const float*)d_in[5];
    const float* bs1 = (const float*)d_in[6];
    const float* Ws2 = (const float*)d_in[7];
    const float* bs2 = (const float*)d_in[8];
    float* out = (float*)d_out;

    unsigned char* wsb = (unsigned char*)d_ws;
    unsigned short* spb    = (unsigned short*)(wsb);                    // 512 KB
    unsigned short* tpb    = (unsigned short*)(wsb + (512u<<10));       // 512 KB
    unsigned short* adj_b  = (unsigned short*)(wsb + (1024u<<10));      // 2 MB
    unsigned short* adj_bt = (unsigned short*)(wsb + (3072u<<10));      // 2 MB
    unsigned short* a2b    = (unsigned short*)(wsb + (5120u<<10));      // 2 MB
    unsigned int*   maxslot= (unsigned int*)(wsb + (7168u<<10));        // 16 B

    k_enc  <<<dim3(512),     256, 0, stream>>>(x, W1, b1, W2, b2, Ws1, bs1, spb, tpb, maxslot);
    k_score<<<dim3(8, 8, Bn),256, 0, stream>>>(spb, tpb, Ws2, bs2, adj_b, adj_bt);
    k_mm1  <<<dim3(8, 8, Bn),256, 0, stream>>>(adj_b, adj_bt, a2b);
    k_mm2  <<<dim3(8, 8, Bn),256, 0, stream>>>(adj_b, adj_bt, a2b, out, maxslot);
    k_norm <<<dim3(1024),    256, 0, stream>>>(out, maxslot);
}

// Round 8
// 152.151 us; speedup vs baseline: 1.6182x; 1.6182x over previous
//
#include <hip/hip_runtime.h>
#include <math.h>

#define Bn 4
#define Tn 12
#define Nn 512
#define Dn 128
#define Ln 4
#define Hn 64
#define NNe (Nn*Nn)

typedef __attribute__((ext_vector_type(8))) short short8;
typedef __attribute__((ext_vector_type(4))) float f32x4;

__device__ __forceinline__ unsigned short f2bf(float f) {
    unsigned int u = __float_as_uint(f);
    unsigned int r = (u + 0x7FFF + ((u >> 16) & 1)) >> 16;   // RNE
    return (unsigned short)r;
}
__device__ __forceinline__ float bf2f(unsigned short s) {
    return __uint_as_float(((unsigned int)s) << 16);
}

// ============ K1a: h = relu(x_lag @ W1[l] + b1[l]) -> bf16 global ============
// 512 blocks = (2048/16 row-groups) x 4 lags; wave = 4 rows; lane = h-channel.
// Short 32-iter chain, no manual prefetch, unroll-1 outer loop (R5/R7: spills).
__global__ __launch_bounds__(256) void k_enc_a(
    const float* __restrict__ x, const float* __restrict__ W1, const float* __restrict__ b1,
    unsigned short* __restrict__ hb, unsigned int* __restrict__ maxslot)
{
    int tid = threadIdx.x, bx = blockIdx.x;
    if (bx == 0 && tid < Bn) maxslot[tid] = 0u;
    int wv = __builtin_amdgcn_readfirstlane(tid >> 6);
    int lane = tid & 63;
    int lag = bx & 3;
    int r0 = (bx >> 2) * 16 + wv * 4;      // 16-row groups never straddle a batch
    int bb = r0 >> 9, n0 = r0 & 511;
    const float* xr = x + ((size_t)(bb*Tn + (Tn-1-lag))*Nn + n0) * Dn;
    const float* Wp = W1 + (size_t)lag*Dn*Hn;
    float acc[4] = {0.f, 0.f, 0.f, 0.f};
    #pragma unroll 1
    for (int d4 = 0; d4 < 32; ++d4) {
        float4 xv[4];
        #pragma unroll
        for (int r = 0; r < 4; ++r) xv[r] = *(const float4*)(xr + r*Dn + d4*4);  // wave-uniform
        #pragma unroll
        for (int u = 0; u < 4; ++u) {
            float w = Wp[(d4*4+u)*Hn + lane];                // coalesced 4B/lane
            #pragma unroll
            for (int r = 0; r < 4; ++r) acc[r] += ((const float*)&xv[r])[u]*w;
        }
    }
    float bv = b1[lag*Hn + lane];
    #pragma unroll
    for (int r = 0; r < 4; ++r)
        hb[((size_t)(r0+r)*Ln + lag)*Hn + lane] = f2bf(fmaxf(acc[r]+bv, 0.f));
}

// ============ K1b: agg = 0.25 * (sum_l h_l @ W2[l] + sum b2) -> bf16 global ============
// 512 blocks x 4 rows; wave = (row-pair, d-half); lane = d.
__global__ __launch_bounds__(256) void k_enc_b(
    const unsigned short* __restrict__ hb, const float* __restrict__ W2,
    const float* __restrict__ b2, unsigned short* __restrict__ aggb)
{
    int tid = threadIdx.x, bx = blockIdx.x;
    int wv = __builtin_amdgcn_readfirstlane(tid >> 6);
    int lane = tid & 63;
    int r0 = bx*4 + (wv >> 1)*2;
    int d  = (wv & 1)*64 + lane;
    const unsigned short* h0 = hb + (size_t)r0*Ln*Hn;
    const unsigned short* h1 = h0 + Ln*Hn;
    float acc0 = 0.f, acc1 = 0.f;
    #pragma unroll 1
    for (int l = 0; l < Ln; ++l) {
        const float* Wp = W2 + (size_t)l*Hn*Dn + d;
        #pragma unroll 1
        for (int h4 = 0; h4 < 16; ++h4) {
            ushort4 u0 = *(const ushort4*)(h0 + l*Hn + h4*4);   // wave-uniform 8B
            ushort4 u1 = *(const ushort4*)(h1 + l*Hn + h4*4);
            float w0 = Wp[(size_t)(h4*4+0)*Dn];
            float w1 = Wp[(size_t)(h4*4+1)*Dn];
            float w2 = Wp[(size_t)(h4*4+2)*Dn];
            float w3 = Wp[(size_t)(h4*4+3)*Dn];
            acc0 += bf2f(u0.x)*w0 + bf2f(u0.y)*w1 + bf2f(u0.z)*w2 + bf2f(u0.w)*w3;
            acc1 += bf2f(u1.x)*w0 + bf2f(u1.y)*w1 + bf2f(u1.z)*w2 + bf2f(u1.w)*w3;
        }
    }
    float b2s = b2[d] + b2[Dn+d] + b2[2*Dn+d] + b2[3*Dn+d];
    aggb[(size_t)r0*Dn + d]     = f2bf(0.25f*(acc0 + b2s));
    aggb[(size_t)(r0+1)*Dn + d] = f2bf(0.25f*(acc1 + b2s));
}

// ============ K1c: sp = agg@Ws1[:D]+bs1, tp = agg@Ws1[D:] -> bf16 global ============
// 512 blocks x 4 rows; wave = (row-pair, tgt); lane = k (two k-halves in regs).
__global__ __launch_bounds__(256) void k_enc_c(
    const unsigned short* __restrict__ aggb, const float* __restrict__ Ws1,
    const float* __restrict__ bs1,
    unsigned short* __restrict__ spb, unsigned short* __restrict__ tpb)
{
    int tid = threadIdx.x, bx = blockIdx.x;
    int wv = __builtin_amdgcn_readfirstlane(tid >> 6);
    int lane = tid & 63;
    int r0 = bx*4 + (wv >> 1)*2;
    int tgt = wv & 1;
    const unsigned short* a0 = aggb + (size_t)r0*Dn;
    const unsigned short* a1 = a0 + Dn;
    const float* Wb = Ws1 + (size_t)tgt*Dn*Dn + lane;
    float s00 = 0.f, s01 = 0.f, s10 = 0.f, s11 = 0.f;   // [row][k-half]
    #pragma unroll 1
    for (int d4 = 0; d4 < 32; ++d4) {
        ushort4 u0 = *(const ushort4*)(a0 + d4*4);      // wave-uniform 8B
        ushort4 u1 = *(const ushort4*)(a1 + d4*4);
        #pragma unroll
        for (int u = 0; u < 4; ++u) {
            float w0 = Wb[(size_t)(d4*4+u)*Dn];          // coalesced 4B/lane
            float w1 = Wb[(size_t)(d4*4+u)*Dn + 64];
            float a0v = bf2f(((const unsigned short*)&u0)[u]);
            float a1v = bf2f(((const unsigned short*)&u1)[u]);
            s00 += a0v*w0; s01 += a0v*w1;
            s10 += a1v*w0; s11 += a1v*w1;
        }
    }
    float bv0 = (tgt == 0) ? bs1[lane]      : 0.f;       // fold bs1 into sp
    float bv1 = (tgt == 0) ? bs1[lane + 64] : 0.f;
    unsigned short* dst = tgt ? tpb : spb;
    dst[(size_t)r0*Dn + lane]          = f2bf(s00 + bv0);
    dst[(size_t)r0*Dn + lane + 64]     = f2bf(s01 + bv1);
    dst[(size_t)(r0+1)*Dn + lane]      = f2bf(s10 + bv0);
    dst[(size_t)(r0+1)*Dn + lane + 64] = f2bf(s11 + bv1);
}

// ============ K2: pairwise scorer -> adj bf16 row-major + transposed ============
__global__ __launch_bounds__(256) void k_score(
    const unsigned short* __restrict__ spb, const unsigned short* __restrict__ tpb,
    const float* __restrict__ Ws2, const float* __restrict__ bs2,
    unsigned short* __restrict__ adj_b, unsigned short* __restrict__ adj_bt)
{
    __shared__ float spl[64*132];                     // 33 KB
    __shared__ unsigned short tplT[Dn*72];            // 18 KB
    int tid = threadIdx.x;
    int wv = __builtin_amdgcn_readfirstlane(tid >> 6);
    int lane = tid & 63;
    int bz = blockIdx.z;
    int i0b = blockIdx.y * 64, j0b = blockIdx.x * 64;
    const unsigned short* spr = spb + (size_t)bz*Nn*Dn;
    const unsigned short* tpr = tpb + (size_t)bz*Nn*Dn;

    for (int v = tid; v < 1024; v += 256) {           // sp tile: bf16 -> fp32 LDS
        int row = v >> 4, c = v & 15;
        const unsigned short* src = spr + (size_t)(i0b+row)*Dn + c*8;
        ushort4 u0 = *(const ushort4*)src;
        ushort4 u1 = *(const ushort4*)(src + 4);
        float4 f0 = { bf2f(u0.x), bf2f(u0.y), bf2f(u0.z), bf2f(u0.w) };
        float4 f1 = { bf2f(u1.x), bf2f(u1.y), bf2f(u1.z), bf2f(u1.w) };
        *(float4*)&spl[row*132 + c*8]     = f0;
        *(float4*)&spl[row*132 + c*8 + 4] = f1;
    }
    {   // tp tile transposed, bf16
        int j = tid & 63, kq = tid >> 6;
        for (int p = 0; p < 4; ++p) {
            int k8 = p*4 + kq;
            short8 tv = *(const short8*)(tpr + (size_t)(j0b+j)*Dn + k8*8);
            #pragma unroll
            for (int t = 0; t < 8; ++t) tplT[(k8*8+t)*72 + j] = (unsigned short)tv[t];
        }
    }
    __syncthreads();

    int iq = lane >> 4, jq = lane & 15;
    int iw = wv*16 + iq*4;
    float acc[4][4] = {};
    for (int k8 = 0; k8 < 16; ++k8) {
        float4 wa = *(const float4*)(Ws2 + k8*8);     // uniform -> scalar path
        float4 wb = *(const float4*)(Ws2 + k8*8 + 4);
        float4 sA[4], sB[4];
        #pragma unroll
        for (int ii = 0; ii < 4; ++ii) {
            sA[ii] = *(const float4*)&spl[(iw+ii)*132 + k8*8];
            sB[ii] = *(const float4*)&spl[(iw+ii)*132 + k8*8 + 4];
        }
        ushort4 t4[8];
        #pragma unroll
        for (int kk = 0; kk < 8; ++kk) t4[kk] = *(const ushort4*)&tplT[(k8*8+kk)*72 + jq*4];
        #pragma unroll
        for (int kk = 0; kk < 8; ++kk) {
            float w = (kk < 4) ? ((const float*)&wa)[kk] : ((const float*)&wb)[kk-4];
            float tv0 = bf2f(t4[kk].x), tv1 = bf2f(t4[kk].y);
            float tv2 = bf2f(t4[kk].z), tv3 = bf2f(t4[kk].w);
            #pragma unroll
            for (int ii = 0; ii < 4; ++ii) {
                float s = (kk < 4) ? ((const float*)&sA[ii])[kk] : ((const float*)&sB[ii])[kk-4];
                acc[ii][0] += fmaxf(s + tv0, 0.f)*w;
                acc[ii][1] += fmaxf(s + tv1, 0.f)*w;
                acc[ii][2] += fmaxf(s + tv2, 0.f)*w;
                acc[ii][3] += fmaxf(s + tv3, 0.f)*w;
            }
        }
    }
    float bsv = bs2[0];
    int i0 = i0b + iw;
    int j0 = j0b + jq*4;
    float vals[4][4];
    #pragma unroll
    for (int ii = 0; ii < 4; ++ii) {
        int i = i0 + ii;
        #pragma unroll
        for (int jj = 0; jj < 4; ++jj) {
            float z = acc[ii][jj] + bsv;
            float sc = 1.f/(1.f + __expf(-z));
            int j = j0 + jj;
            vals[ii][jj] = (sc > 0.1f && i != j) ? sc : 0.f;
        }
    }
    size_t base = (size_t)bz << 18;
    #pragma unroll
    for (int ii = 0; ii < 4; ++ii) {
        ushort4 rv = make_ushort4(f2bf(vals[ii][0]), f2bf(vals[ii][1]),
                                  f2bf(vals[ii][2]), f2bf(vals[ii][3]));
        *(ushort4*)(adj_b + base + (size_t)(i0+ii)*Nn + j0) = rv;
    }
    #pragma unroll
    for (int jj = 0; jj < 4; ++jj) {
        ushort4 cv = make_ushort4(f2bf(vals[0][jj]), f2bf(vals[1][jj]),
                                  f2bf(vals[2][jj]), f2bf(vals[3][jj]));
        *(ushort4*)(adj_bt + base + (size_t)(j0+jj)*Nn + i0) = cv;
    }
}

// ============ K3: a2 = adj @ adj (MFMA, 64x64 tile, BK=64, reg double-buffer) ============
__global__ __launch_bounds__(256) void k_mm1(
    const unsigned short* __restrict__ adj_b, const unsigned short* __restrict__ adj_bt,
    unsigned short* __restrict__ a2b)
{
    __shared__ unsigned short Als[64*72];
    __shared__ unsigned short Bls[64*72];
    int tid = threadIdx.x;
    int wv = __builtin_amdgcn_readfirstlane(tid >> 6);
    int lane = tid & 63;
    int b = blockIdx.z, i0 = blockIdx.y*64, j0 = blockIdx.x*64;
    size_t base = (size_t)b << 18;
    const unsigned short* Ab = adj_b + base;
    const unsigned short* Bb = adj_bt + base;
    int wm = wv >> 1, wn = wv & 1;
    int m = lane & 15, q = lane >> 4;
    int sr = tid >> 2, sc = (tid & 3)*16;
    f32x4 acc[2][2];
    #pragma unroll
    for (int mt = 0; mt < 2; ++mt)
        #pragma unroll
        for (int nt = 0; nt < 2; ++nt) acc[mt][nt] = (f32x4){0.f,0.f,0.f,0.f};
    short8 pa0, pa1, pb0, pb1;
    pa0 = *(const short8*)(Ab + (size_t)(i0+sr)*Nn + sc);
    pa1 = *(const short8*)(Ab + (size_t)(i0+sr)*Nn + sc + 8);
    pb0 = *(const short8*)(Bb + (size_t)(j0+sr)*Nn + sc);
    pb1 = *(const short8*)(Bb + (size_t)(j0+sr)*Nn + sc + 8);
    for (int kt = 0; kt < 8; ++kt) {
        *(short8*)&Als[sr*72 + sc]     = pa0;
        *(short8*)&Als[sr*72 + sc + 8] = pa1;
        *(short8*)&Bls[sr*72 + sc]     = pb0;
        *(short8*)&Bls[sr*72 + sc + 8] = pb1;
        __syncthreads();
        if (kt < 7) {
            int k0 = (kt+1)*64;
            pa0 = *(const short8*)(Ab + (size_t)(i0+sr)*Nn + k0 + sc);
            pa1 = *(const short8*)(Ab + (size_t)(i0+sr)*Nn + k0 + sc + 8);
            pb0 = *(const short8*)(Bb + (size_t)(j0+sr)*Nn + k0 + sc);
            pb1 = *(const short8*)(Bb + (size_t)(j0+sr)*Nn + k0 + sc + 8);
        }
        #pragma unroll
        for (int ks = 0; ks < 2; ++ks) {
            short8 af[2], bg[2];
            #pragma unroll
            for (int mt = 0; mt < 2; ++mt) af[mt] = *(const short8*)&Als[(wm*32+mt*16+m)*72 + ks*32 + q*8];
            #pragma unroll
            for (int nt = 0; nt < 2; ++nt) bg[nt] = *(const short8*)&Bls[(wn*32+nt*16+m)*72 + ks*32 + q*8];
            #pragma unroll
            for (int mt = 0; mt < 2; ++mt)
                #pragma unroll
                for (int nt = 0; nt < 2; ++nt)
                    acc[mt][nt] = __builtin_amdgcn_mfma_f32_16x16x32_bf16(af[mt], bg[nt], acc[mt][nt], 0, 0, 0);
        }
        __syncthreads();
    }
    int col = lane & 15, rq = lane >> 4;
    #pragma unroll
    for (int mt = 0; mt < 2; ++mt)
        #pragma unroll
        for (int nt = 0; nt < 2; ++nt)
            #pragma unroll
            for (int reg = 0; reg < 4; ++reg) {
                int i = i0 + wm*32 + mt*16 + rq*4 + reg;
                int j = j0 + wn*32 + nt*16 + col;
                a2b[base + (size_t)i*Nn + j] = f2bf(acc[mt][nt][reg]);
            }
}

// ============ K4: out = adj + 0.5*a2 + 0.25*(a2@adj), + per-batch max ============
__global__ __launch_bounds__(256) void k_mm2(
    const unsigned short* __restrict__ adj_b, const unsigned short* __restrict__ adj_bt,
    const unsigned short* __restrict__ a2b,
    float* __restrict__ out, unsigned int* __restrict__ maxslot)
{
    __shared__ unsigned short Als[64*72];
    __shared__ unsigned short Bls[64*72];
    __shared__ float red[4];
    int tid = threadIdx.x;
    int wv = __builtin_amdgcn_readfirstlane(tid >> 6);
    int lane = tid & 63;
    int b = blockIdx.z, i0 = blockIdx.y*64, j0 = blockIdx.x*64;
    size_t base = (size_t)b << 18;
    const unsigned short* Ab = a2b + base;       // A = a2
    const unsigned short* Bb = adj_bt + base;    // B = adj (transposed layout)
    int wm = wv >> 1, wn = wv & 1;
    int m = lane & 15, q = lane >> 4;
    int sr = tid >> 2, sc = (tid & 3)*16;
    f32x4 acc[2][2];
    #pragma unroll
    for (int mt = 0; mt < 2; ++mt)
        #pragma unroll
        for (int nt = 0; nt < 2; ++nt) acc[mt][nt] = (f32x4){0.f,0.f,0.f,0.f};
    short8 pa0, pa1, pb0, pb1;
    pa0 = *(const short8*)(Ab + (size_t)(i0+sr)*Nn + sc);
    pa1 = *(const short8*)(Ab + (size_t)(i0+sr)*Nn + sc + 8);
    pb0 = *(const short8*)(Bb + (size_t)(j0+sr)*Nn + sc);
    pb1 = *(const short8*)(Bb + (size_t)(j0+sr)*Nn + sc + 8);
    for (int kt = 0; kt < 8; ++kt) {
        *(short8*)&Als[sr*72 + sc]     = pa0;
        *(short8*)&Als[sr*72 + sc + 8] = pa1;
        *(short8*)&Bls[sr*72 + sc]     = pb0;
        *(short8*)&Bls[sr*72 + sc + 8] = pb1;
        __syncthreads();
        if (kt < 7) {
            int k0 = (kt+1)*64;
            pa0 = *(const short8*)(Ab + (size_t)(i0+sr)*Nn + k0 + sc);
            pa1 = *(const short8*)(Ab + (size_t)(i0+sr)*Nn + k0 + sc + 8);
            pb0 = *(const short8*)(Bb + (size_t)(j0+sr)*Nn + k0 + sc);
            pb1 = *(const short8*)(Bb + (size_t)(j0+sr)*Nn + k0 + sc + 8);
        }
        #pragma unroll
        for (int ks = 0; ks < 2; ++ks) {
            short8 af[2], bg[2];
            #pragma unroll
            for (int mt = 0; mt < 2; ++mt) af[mt] = *(const short8*)&Als[(wm*32+mt*16+m)*72 + ks*32 + q*8];
            #pragma unroll
            for (int nt = 0; nt < 2; ++nt) bg[nt] = *(const short8*)&Bls[(wn*32+nt*16+m)*72 + ks*32 + q*8];
            #pragma unroll
            for (int mt = 0; mt < 2; ++mt)
                #pragma unroll
                for (int nt = 0; nt < 2; ++nt)
                    acc[mt][nt] = __builtin_amdgcn_mfma_f32_16x16x32_bf16(af[mt], bg[nt], acc[mt][nt], 0, 0, 0);
        }
        __syncthreads();
    }
    int col = lane & 15, rq = lane >> 4;
    float lmax = 0.f;
    const unsigned short* adjp = adj_b + base;
    #pragma unroll
    for (int mt = 0; mt < 2; ++mt)
        #pragma unroll
        for (int nt = 0; nt < 2; ++nt)
            #pragma unroll
            for (int reg = 0; reg < 4; ++reg) {
                int i = i0 + wm*32 + mt*16 + rq*4 + reg;
                int j = j0 + wn*32 + nt*16 + col;
                size_t off = (size_t)i*Nn + j;
                float e = bf2f(adjp[off]) + 0.5f*bf2f(Ab[off]) + 0.25f*acc[mt][nt][reg];
                out[base + off] = e;
                lmax = fmaxf(lmax, e);
            }
    #pragma unroll
    for (int s = 1; s < 64; s <<= 1) lmax = fmaxf(lmax, __shfl_xor(lmax, s, 64));
    if (lane == 0) red[wv] = lmax;
    __syncthreads();
    if (tid == 0) {
        float mx = fmaxf(fmaxf(red[0], red[1]), fmaxf(red[2], red[3]));
        atomicMax(maxslot + b, __float_as_uint(mx));
    }
}

// ============ K5: out /= (max + 1e-8) ============
__global__ __launch_bounds__(256) void k_norm(float* __restrict__ out,
                                              const unsigned int* __restrict__ maxslot)
{
    int idx = blockIdx.x*256 + threadIdx.x;   // float4 index; 65536 per batch
    int b = idx >> 16;
    float m = __uint_as_float(maxslot[b]);
    float inv = 1.f/(m + 1e-8f);
    float4* p = (float4*)out + idx;
    float4 v = *p;
    v.x *= inv; v.y *= inv; v.z *= inv; v.w *= inv;
    *p = v;
}

extern "C" void kernel_launch(void* const* d_in, const int* in_sizes, int n_in,
                              void* d_out, int out_size, void* d_ws, size_t ws_size,
                              hipStream_t stream) {
    const float* x   = (const float*)d_in[0];
    const float* W1  = (const float*)d_in[1];
    const float* b1  = (const float*)d_in[2];
    const float* W2  = (const float*)d_in[3];
    const float* b2  = (const float*)d_in[4];
    const float* Ws1 = (const float*)d_in[5];
    const float* bs1 = (const float*)d_in[6];
    const float* Ws2 = (const float*)d_in[7];
    const float* bs2 = (const float*)d_in[8];
    float* out = (float*)d_out;

    unsigned char* wsb = (unsigned char*)d_ws;
    unsigned short* spb    = (unsigned short*)(wsb);                    // 512 KB
    unsigned short* tpb    = (unsigned short*)(wsb + (512u<<10));       // 512 KB
    unsigned short* adj_b  = (unsigned short*)(wsb + (1024u<<10));      // 2 MB
    unsigned short* adj_bt = (unsigned short*)(wsb + (3072u<<10));      // 2 MB
    unsigned short* a2b    = (unsigned short*)(wsb + (5120u<<10));      // 2 MB
    unsigned int*   maxslot= (unsigned int*)(wsb + (7168u<<10));        // 16 B
    unsigned short* hb     = (unsigned short*)(wsb + (7172u<<10));      // 1 MB  [row][lag][64]
    unsigned short* aggb   = (unsigned short*)(wsb + (8196u<<10));      // 512 KB [row][128]

    k_enc_a<<<dim3(512),     256, 0, stream>>>(x, W1, b1, hb, maxslot);
    k_enc_b<<<dim3(512),     256, 0, stream>>>(hb, W2, b2, aggb);
    k_enc_c<<<dim3(512),     256, 0, stream>>>(aggb, Ws1, bs1, spb, tpb);
    k_score<<<dim3(8, 8, Bn),256, 0, stream>>>(spb, tpb, Ws2, bs2, adj_b, adj_bt);
    k_mm1  <<<dim3(8, 8, Bn),256, 0, stream>>>(adj_b, adj_bt, a2b);
    k_mm2  <<<dim3(8, 8, Bn),256, 0, stream>>>(adj_b, adj_bt, a2b, out, maxslot);
    k_norm <<<dim3(1024),    256, 0, stream>>>(out, maxslot);
}